// Round 5
// baseline (307.734 us; speedup 1.0000x reference)
//
#include <hip/hip_runtime.h>
#include <stdint.h>

typedef __attribute__((ext_vector_type(8))) __bf16 bf16x8;
typedef __attribute__((ext_vector_type(4))) float f32x4;
typedef __attribute__((ext_vector_type(16))) float f32x16;
typedef __attribute__((ext_vector_type(4))) uint32_t u32x4;

#define DEVINL __device__ __forceinline__

constexpr int Bc = 2, Sc = 2048, Dc = 1024, Hc = 16;
constexpr int MSc = Bc * Sc;  // 4096 total rows
constexpr float LN_EPS_C = 1e-3f;
constexpr float QSCALE = 0.125f * 1.44269504f;  // 1/sqrt(64) * log2(e)

// ---- global -> LDS direct load, 16B per lane (wave-uniform LDS base).
DEVINL void gload16(const void* gsrc, const void* lds_dst) {
  auto g = (const __attribute__((address_space(1))) void*)(uintptr_t)gsrc;
  auto l = (__attribute__((address_space(3))) void*)(uint32_t)(uintptr_t)lds_dst;
  __builtin_amdgcn_global_load_lds(g, l, 16, 0, 0);
}

// packed f32 pair -> 2x bf16 in one u32 (T12 recipe; no builtin on gfx950)
DEVINL uint32_t cvtpk(float lo, float hi) {
  uint32_t r;
  asm("v_cvt_pk_bf16_f32 %0, %1, %2" : "=v"(r) : "v"(lo), "v"(hi));
  return r;
}

// v_permlane32_swap: a[32:63] <-> b[0:31]
DEVINL void plswap(uint32_t& a, uint32_t& b) {
  asm volatile("v_permlane32_swap_b32 %0, %1" : "+v"(a), "+v"(b));
}

// =====================================================================
// GEMM core: C[M,N] = A[M,K] * Bt[N,K]^T (bf16 row-major, K-contiguous)
// 128xBN tile, BK=64, 256 thr = 4 waves 2x2, 16x16x32 bf16 MFMA.
// LDS XOR-swizzled via pre-swizzled global source (global_load_lds linear).
// epi (runtime): 0 bf16, 1 f32, 2 relu->bf16, 3 bf16 + QSCALE on col<1024
// =====================================================================
template <int BN>
DEVINL void gemm_core(const __bf16* __restrict__ A, const __bf16* __restrict__ Bt,
                      void* __restrict__ Cout, int M, int N, int K, int epi,
                      int blk) {
  __shared__ __bf16 Ash[128 * 64];
  __shared__ __bf16 Bsh[BN * 64];
  constexpr int NF = BN / 32;  // per-wave n-fragments
  const int t = threadIdx.x;
  const int lane = t & 63;
  const int wid = t >> 6;
  const int nbn = N / BN;
  const int bm = blk / nbn, bn = blk % nbn;
  const int m0 = bm * 128, n0 = bn * BN;
  const int wm = wid >> 1, wn = wid & 1;

  f32x4 acc[4][NF];
  f32x4 zero = {0.f, 0.f, 0.f, 0.f};
#pragma unroll
  for (int i = 0; i < 4; ++i)
#pragma unroll
    for (int j = 0; j < NF; ++j) acc[i][j] = zero;

  for (int k0 = 0; k0 < K; k0 += 64) {
#pragma unroll
    for (int i = 0; i < 4; ++i) {
      int c = i * 256 + t;
      int row = c >> 3;
      int ch = (c & 7) ^ (row & 7);
      gload16(A + (size_t)(m0 + row) * K + k0 + ch * 8,
              (const char*)Ash + (i * 256 + wid * 64) * 16);
    }
#pragma unroll
    for (int i = 0; i < BN / 32; ++i) {
      int c = i * 256 + t;
      int row = c >> 3;
      int ch = (c & 7) ^ (row & 7);
      gload16(Bt + (size_t)(n0 + row) * K + k0 + ch * 8,
              (const char*)Bsh + (i * 256 + wid * 64) * 16);
    }
    __syncthreads();
#pragma unroll
    for (int kk = 0; kk < 2; ++kk) {
      bf16x8 af[4], bfr[NF];
      const int colb = kk * 64 + (lane >> 4) * 16;
#pragma unroll
      for (int mf = 0; mf < 4; ++mf) {
        int row = wm * 64 + mf * 16 + (lane & 15);
        af[mf] = *(const bf16x8*)((const char*)Ash + row * 128 +
                                  (colb ^ ((row & 7) << 4)));
      }
#pragma unroll
      for (int nf = 0; nf < NF; ++nf) {
        int row = wn * (BN / 2) + nf * 16 + (lane & 15);
        bfr[nf] = *(const bf16x8*)((const char*)Bsh + row * 128 +
                                   (colb ^ ((row & 7) << 4)));
      }
#pragma unroll
      for (int mf = 0; mf < 4; ++mf)
#pragma unroll
        for (int nf = 0; nf < NF; ++nf)
          acc[mf][nf] = __builtin_amdgcn_mfma_f32_16x16x32_bf16(
              af[mf], bfr[nf], acc[mf][nf], 0, 0, 0);
    }
    __syncthreads();
  }
#pragma unroll
  for (int mf = 0; mf < 4; ++mf)
#pragma unroll
    for (int nf = 0; nf < NF; ++nf)
#pragma unroll
      for (int r = 0; r < 4; ++r) {
        int row = m0 + wm * 64 + mf * 16 + (lane >> 4) * 4 + r;
        int col = n0 + wn * (BN / 2) + nf * 16 + (lane & 15);
        float v = acc[mf][nf][r];
        if (epi == 0)
          ((__bf16*)Cout)[(size_t)row * N + col] = (__bf16)v;
        else if (epi == 1)
          ((float*)Cout)[(size_t)row * N + col] = v;
        else if (epi == 2)
          ((__bf16*)Cout)[(size_t)row * N + col] = (__bf16)fmaxf(v, 0.f);
        else {
          if (col < 1024) v *= QSCALE;
          ((__bf16*)Cout)[(size_t)row * N + col] = (__bf16)v;
        }
      }
}

template <int BN>
__global__ __launch_bounds__(256) void gemm_bt(const __bf16* __restrict__ A,
                                               const __bf16* __restrict__ Bt,
                                               void* __restrict__ Cout, int M,
                                               int N, int K, int epi) {
  gemm_core<BN>(A, Bt, Cout, M, N, K, epi, blockIdx.x);
}

// fused launch: blocks 0-511 -> [Q*c|K] = X [Wq|Wk]; 512-767 -> V^T = Wv^T X^T
__global__ __launch_bounds__(256) void gemm_dual(const __bf16* __restrict__ Xbf,
                                                 const __bf16* __restrict__ Wqk,
                                                 const __bf16* __restrict__ Wvt,
                                                 __bf16* __restrict__ QKb,
                                                 __bf16* __restrict__ Vt) {
  if (blockIdx.x < 512)
    gemm_core<128>(Xbf, Wqk, QKb, MSc, 2048, Dc, 3, blockIdx.x);
  else
    gemm_core<128>(Wvt, Xbf, Vt, Dc, MSc, Dc, 0, blockIdx.x - 512);
}

// =====================================================================
// Flash attention, swapped-QK 32x32, no-max softmax, KV-split=2.
// Partials are linearly combinable (no max): each split writes unnormalized
// O (f32) and l; combine kernel divides. Grid (S/128, H, B*2) = 1024 blocks
// = 4 blocks/CU. l accumulated via MFMA against all-ones A-frag (moves 32
// v_add/kt from the saturated VALU pipe to the 17%-busy MFMA pipe).
// =====================================================================
__global__ __launch_bounds__(256, 4) void attn_kernel(
    const __bf16* __restrict__ QK, const __bf16* __restrict__ Vt,
    float* __restrict__ Op0, float* __restrict__ Op1,
    float* __restrict__ lpart) {
  __shared__ __bf16 Ksh[2][64 * 64];
  __shared__ __bf16 Vsh[2][64 * 64];
  const int t = threadIdx.x, lane = t & 63, wid = t >> 6;
  const int h = blockIdx.y;
  const int b = blockIdx.z >> 1, sp = blockIdx.z & 1;
  const int q0w = blockIdx.x * 128 + wid * 32;
  const int ql = lane & 31, hl = lane >> 5;

  const __bf16* Qp = QK;         // ld 2048, pre-scaled by QSCALE
  const __bf16* Kp = QK + 1024;  // ld 2048

  // Q as B-operand frags: col=q=lane&31, k=d = kk*16 + hl*8 + j
  bf16x8 qf[4];
#pragma unroll
  for (int kk = 0; kk < 4; ++kk)
    qf[kk] = *(const bf16x8*)(Qp + (size_t)(b * Sc + q0w + ql) * 2048 + h * 64 +
                              kk * 16 + hl * 8);

  // all-ones bf16 A-frag for the l row-sum MFMA
  u32x4 uo;
  uo.x = uo.y = uo.z = uo.w = 0x3F803F80u;
  const bf16x8 onesf = __builtin_bit_cast(bf16x8, uo);

  f32x16 oacc[2], lacc;
#pragma unroll
  for (int r = 0; r < 16; ++r) {
    oacc[0][r] = 0.f;
    oacc[1][r] = 0.f;
    lacc[r] = 0.f;
  }

  const int kt0 = sp * 16;  // this split's 16 KV tiles of 64

  auto stage = [&](int buf, int kt) {
#pragma unroll
    for (int i = 0; i < 2; ++i) {
      int c = i * 256 + t;
      int row = c >> 3;
      int ch = (c & 7) ^ (row & 7);
      gload16(Kp + (size_t)(b * Sc + kt * 64 + row) * 2048 + h * 64 + ch * 8,
              (const char*)Ksh[buf] + (i * 256 + wid * 64) * 16);
    }
#pragma unroll
    for (int i = 0; i < 2; ++i) {
      int c = i * 256 + t;
      int row = c >> 3;
      int ch = (c & 7) ^ (row & 7);
      gload16(Vt + (size_t)(h * 64 + row) * MSc + b * Sc + kt * 64 + ch * 8,
              (const char*)Vsh[buf] + (i * 256 + wid * 64) * 16);
    }
  };

  auto body = [&](int kti, int cur) {
    if (kti + 1 < 16) stage(cur ^ 1, kt0 + kti + 1);

    // ---- S^T[ks][q] = K Q^T : A = K-frag (row=ks), B = qf
    f32x16 sacc[2];
#pragma unroll
    for (int mf = 0; mf < 2; ++mf)
#pragma unroll
      for (int r = 0; r < 16; ++r) sacc[mf][r] = 0.f;
#pragma unroll
    for (int kk = 0; kk < 4; ++kk)
#pragma unroll
      for (int mf = 0; mf < 2; ++mf) {
        int row = mf * 32 + ql;
        bf16x8 kf = *(const bf16x8*)((const char*)Ksh[cur] + row * 128 +
                                     ((kk * 32 + hl * 16) ^ ((row & 7) << 4)));
        sacc[mf] =
            __builtin_amdgcn_mfma_f32_32x32x16_bf16(kf, qf[kk], sacc[mf], 0, 0, 0);
      }

    // ---- p = exp2(s); pack to PV B-frags (verified layout, r3)
    bf16x8 pb[4];
#pragma unroll
    for (int mf = 0; mf < 2; ++mf) {
      float p[16];
#pragma unroll
      for (int r = 0; r < 16; ++r) p[r] = __builtin_exp2f(sacc[mf][r]);
#pragma unroll
      for (int g = 0; g < 2; ++g) {
        uint32_t wa = cvtpk(p[8 * g + 0], p[8 * g + 1]);
        uint32_t wb = cvtpk(p[8 * g + 4], p[8 * g + 5]);
        uint32_t wc = cvtpk(p[8 * g + 2], p[8 * g + 3]);
        uint32_t wd = cvtpk(p[8 * g + 6], p[8 * g + 7]);
        plswap(wa, wb);
        plswap(wc, wd);
        u32x4 uw;
        uw.x = wa;  // j=0,1
        uw.y = wc;  // j=2,3
        uw.z = wb;  // j=4,5
        uw.w = wd;  // j=6,7
        pb[mf * 2 + g] = __builtin_bit_cast(bf16x8, uw);
      }
    }

    // ---- O^T += V^T P^T ; l-row via ones-MFMA (all rows of lacc = l[q])
#pragma unroll
    for (int kt2 = 0; kt2 < 4; ++kt2) {
#pragma unroll
      for (int nh = 0; nh < 2; ++nh) {
        int row = nh * 32 + ql;
        bf16x8 vf = *(const bf16x8*)((const char*)Vsh[cur] + row * 128 +
                                     ((kt2 * 32 + hl * 16) ^ ((row & 7) << 4)));
        oacc[nh] =
            __builtin_amdgcn_mfma_f32_32x32x16_bf16(vf, pb[kt2], oacc[nh], 0, 0, 0);
      }
      lacc = __builtin_amdgcn_mfma_f32_32x32x16_bf16(onesf, pb[kt2], lacc, 0, 0, 0);
    }
    __syncthreads();
  };

  stage(0, kt0);
  __syncthreads();
  for (int kp = 0; kp < 8; ++kp) {  // 16 tiles, LDS parity compile-time
    body(2 * kp, 0);
    body(2 * kp + 1, 1);
  }

  // ---- write f32 partials: O unnormalized + l
  float* Ob = sp ? Op1 : Op0;
  float* Op = Ob + (size_t)(b * Sc + q0w + ql) * Dc + h * 64;
#pragma unroll
  for (int nh = 0; nh < 2; ++nh)
#pragma unroll
    for (int g = 0; g < 4; ++g) {
      f32x4 v;
#pragma unroll
      for (int r = 0; r < 4; ++r) v[r] = oacc[nh][4 * g + r];
      *(f32x4*)(Op + nh * 32 + 8 * g + 4 * hl) = v;
    }
  if (hl == 0)
    lpart[((size_t)(sp * Bc + b) * Hc + h) * Sc + q0w + ql] = lacc[0];
}

// combine: ctx = (O0 + O1) / (l0 + l1), bf16
__global__ __launch_bounds__(256) void attn_combine(const float* __restrict__ O0,
                                                    const float* __restrict__ O1,
                                                    const float* __restrict__ lp,
                                                    __bf16* __restrict__ ctx) {
  const int r = blockIdx.x, t = threadIdx.x;
  const int d0 = t * 4, h = d0 >> 6;
  const int b = r >> 11, s = r & 2047;
  const float l0 = lp[((size_t)(0 * Bc + b) * Hc + h) * Sc + s];
  const float l1 = lp[((size_t)(1 * Bc + b) * Hc + h) * Sc + s];
  const float inv = 1.f / (l0 + l1);
  const f32x4 a = *(const f32x4*)(O0 + (size_t)r * Dc + d0);
  const f32x4 c = *(const f32x4*)(O1 + (size_t)r * Dc + d0);
  union {
    __bf16 hv[4];
    uint2 u;
  } w;
#pragma unroll
  for (int i = 0; i < 4; ++i) w.hv[i] = (__bf16)((a[i] + c[i]) * inv);
  *(uint2*)(ctx + (size_t)r * Dc + d0) = w.u;
}

// =====================================================================
// LayerNorm over last dim (1024) of X+R, one row per block (256 thr).
// MODE 0: write bf16 + f32 residual; MODE 1: f32 only.
// =====================================================================
template <int MODE>
__global__ __launch_bounds__(256) void ln_fused(const float* __restrict__ X,
                                                const float* __restrict__ R,
                                                const float* __restrict__ gamma,
                                                const float* __restrict__ beta,
                                                __bf16* __restrict__ out_bf,
                                                float* __restrict__ out_f) {
  const int row = blockIdx.x;
  const int t = threadIdx.x;
  const f32x4 xv = *(const f32x4*)(X + (size_t)row * Dc + t * 4);
  const f32x4 rv = *(const f32x4*)(R + (size_t)row * Dc + t * 4);
  float x[4];
  float s = 0.f, ss = 0.f;
#pragma unroll
  for (int i = 0; i < 4; ++i) {
    x[i] = xv[i] + rv[i];
    s += x[i];
    ss += x[i] * x[i];
  }
#pragma unroll
  for (int m = 1; m < 64; m <<= 1) {
    s += __shfl_xor(s, m);
    ss += __shfl_xor(ss, m);
  }
  __shared__ float sred[8];
  const int wid = t >> 6, lane = t & 63;
  if (lane == 0) {
    sred[wid * 2] = s;
    sred[wid * 2 + 1] = ss;
  }
  __syncthreads();
  s = sred[0] + sred[2] + sred[4] + sred[6];
  ss = sred[1] + sred[3] + sred[5] + sred[7];
  const float mu = s * (1.f / Dc);
  const float var = ss * (1.f / Dc) - mu * mu;
  const float rstd = rsqrtf(var + LN_EPS_C);
  const f32x4 gv = *(const f32x4*)(gamma + t * 4);
  const f32x4 bv = *(const f32x4*)(beta + t * 4);
#pragma unroll
  for (int i = 0; i < 4; ++i) {
    float y = (x[i] - mu) * rstd * gv[i] + bv[i];
    if (MODE == 0) {
      out_bf[(size_t)row * Dc + t * 4 + i] = (__bf16)y;
      out_f[(size_t)row * Dc + t * 4 + i] = y;
    } else {
      out_f[(size_t)row * Dc + t * 4 + i] = y;
    }
  }
}

// ---- transpose + cast all six weights: W[fi][fo] f32 -> Wt[fo][fi] bf16
__global__ __launch_bounds__(256) void wtrans(const float* __restrict__ w0,
                                              const float* __restrict__ w1,
                                              const float* __restrict__ w2,
                                              const float* __restrict__ w3,
                                              const float* __restrict__ w4,
                                              const float* __restrict__ w5,
                                              __bf16* __restrict__ out) {
  const float* ws[6] = {w0, w1, w2, w3, w4, w5};
  const float* w = ws[blockIdx.z];
  __bf16* o = out + (size_t)blockIdx.z * Dc * Dc;
  __shared__ float tile[32][33];
  const int tx = threadIdx.x, ty = threadIdx.y;  // 32 x 8
  const int c0 = blockIdx.x * 32, r0 = blockIdx.y * 32;
#pragma unroll
  for (int i = 0; i < 4; ++i)
    tile[ty + i * 8][tx] = w[(size_t)(r0 + ty + i * 8) * Dc + c0 + tx];
  __syncthreads();
#pragma unroll
  for (int i = 0; i < 4; ++i)
    o[(size_t)(c0 + ty + i * 8) * Dc + r0 + tx] = (__bf16)tile[tx][ty + i * 8];
}

// ---- f32 -> bf16 cast, 4 elements/thread
__global__ __launch_bounds__(256) void castq(const float* __restrict__ in,
                                             __bf16* __restrict__ out, int n4) {
  int i = blockIdx.x * blockDim.x + threadIdx.x;
  if (i < n4) {
    f32x4 v = *(const f32x4*)(in + (size_t)i * 4);
#pragma unroll
    for (int j = 0; j < 4; ++j) out[(size_t)i * 4 + j] = (__bf16)v[j];
  }
}

extern "C" void kernel_launch(void* const* d_in, const int* in_sizes, int n_in,
                              void* d_out, int out_size, void* d_ws,
                              size_t ws_size, hipStream_t stream) {
  const float* query = (const float*)d_in[0];
  const float* Wq = (const float*)d_in[1];
  const float* Wk = (const float*)d_in[2];
  const float* Wv = (const float*)d_in[3];
  const float* W1 = (const float*)d_in[4];
  const float* W2 = (const float*)d_in[5];
  const float* W3 = (const float*)d_in[6];
  const float* gamma = (const float*)d_in[7];
  const float* beta = (const float*)d_in[8];
  float* out = (float*)d_out;

  char* ws = (char*)d_ws;
  const size_t MB = 1u << 20;
  __bf16* Wt = (__bf16*)(ws);              // 6 x 2MB: [Wq;Wk;Wv;W1;W2;W3]^T
  __bf16* Xbf = (__bf16*)(ws + 12 * MB);   // 8MB
  __bf16* QKb = (__bf16*)(ws + 20 * MB);   // 16MB  [4096 x 2048] = [Q*c | K]
  __bf16* Vt = (__bf16*)(ws + 36 * MB);    // 8MB   V^T [D, B*S]
  __bf16* Ctx = (__bf16*)(ws + 44 * MB);   // 8MB
  float* T1 = (float*)(ws + 52 * MB);      // 16MB; also attn Opart0
  __bf16* Rbf = (__bf16*)(ws + 68 * MB);   // 8MB
  float* Rf = (float*)(ws + 76 * MB);      // 16MB; also attn Opart1
  __bf16* H2 = (__bf16*)(ws + 92 * MB);    // 8MB; first 512KB = attn lpart

  const int WD = Dc * Dc;
  float* Op0 = T1;            // consumed by combine before W1 writes T1
  float* Op1 = Rf;            // consumed by combine before ln0 writes Rf
  float* lpart = (float*)H2;  // consumed by combine before W2 writes H2

  wtrans<<<dim3(32, 32, 6), dim3(32, 8), 0, stream>>>(Wq, Wk, Wv, W1, W2, W3, Wt);
  castq<<<4096, 256, 0, stream>>>(query, Xbf, (MSc * Dc) / 4);
  // fused: [Q*c|K] = X [Wq|Wk] (512 blk) || V^T = Wv^T X^T (256 blk)
  gemm_dual<<<768, 256, 0, stream>>>(Xbf, Wt, Wt + 2 * WD, QKb, Vt);
  attn_kernel<<<dim3(Sc / 128, Hc, Bc * 2), 256, 0, stream>>>(QKb, Vt, Op0, Op1,
                                                              lpart);
  attn_combine<<<MSc, 256, 0, stream>>>(Op0, Op1, lpart, Ctx);
  // T1 = ctx W1 (f32)
  gemm_bt<64><<<32 * 16, 256, 0, stream>>>(Ctx, Wt + 3 * WD, T1, MSc, Dc, Dc, 1);
  // residual = LN(T1 + query) -> Rbf (bf16) + Rf (f32)
  ln_fused<0><<<MSc, 256, 0, stream>>>(T1, query, gamma, beta, Rbf, Rf);
  // H2 = relu(residual W2) (bf16)
  gemm_bt<64><<<32 * 16, 256, 0, stream>>>(Rbf, Wt + 4 * WD, H2, MSc, Dc, Dc, 2);
  // T1 = H2 W3 (f32)
  gemm_bt<64><<<32 * 16, 256, 0, stream>>>(H2, Wt + 5 * WD, T1, MSc, Dc, Dc, 1);
  // out = LN(T1 + residual)
  ln_fused<1><<<MSc, 256, 0, stream>>>(T1, Rf, gamma, beta, nullptr, out);
}